// Round 4
// baseline (774.521 us; speedup 1.0000x reference)
//
#include <hip/hip_runtime.h>

typedef unsigned short u16;
typedef unsigned int   u32;

#define E_TOT 160000
#define TPB   128
#define NBLK  1250       // 1250*128 == 160000 exactly
#define ARENA 83         // f32 words/thread: ef[0..16] | h1[18..49] | s0[50..57] | s1[58..81] | pad

struct P4 { const float *w1, *b1, *w2, *b2, *w3, *b3; };

// radial MLP: ef in A[0..16], h1 staged f32 in A[18..49], h2 -> regs
__device__ __forceinline__ void mlp_f32(float* __restrict__ A, P4 W, float (&h2)[32])
{
  float h[32];
  #pragma unroll
  for (int m = 0; m < 32; ++m) h[m] = W.b1[m];
  #pragma unroll 1
  for (int k = 0; k < 17; ++k){
    float x = A[k];
    const float* __restrict__ r = W.w1 + k * 32;   // row-major (17,32), row k
    #pragma unroll
    for (int m = 0; m < 32; ++m) h[m] = fmaf(x, r[m], h[m]);
  }
  #pragma unroll
  for (int m = 0; m < 32; ++m) A[18 + m] = fmaxf(h[m], 0.f);
  #pragma unroll
  for (int m = 0; m < 32; ++m) h2[m] = W.b2[m];
  #pragma unroll 1
  for (int k = 0; k < 32; ++k){
    float x = A[18 + k];
    const float* __restrict__ r = W.w2 + k * 32;   // row-major (32,32), row k
    #pragma unroll
    for (int m = 0; m < 32; ++m) h2[m] = fmaf(x, r[m], h2[m]);
  }
  #pragma unroll
  for (int m = 0; m < 32; ++m) h2[m] = fmaxf(h2[m], 0.f);
}

// column dot: sum_m h2[m] * w3[m*C + c]  (w3 row-major (32, C), c wave-uniform)
__device__ __forceinline__ float coldot64(const float (&h)[32], const float* __restrict__ w3, int c){
  float a0 = 0.f, a1 = 0.f;
  #pragma unroll
  for (int m = 0; m < 32; m += 2){
    a0 = fmaf(h[m],   w3[m * 64 + c],       a0);
    a1 = fmaf(h[m+1], w3[(m+1) * 64 + c],   a1);
  }
  return a0 + a1;
}
__device__ __forceinline__ float coldot192(const float (&h)[32], const float* __restrict__ w3, int c){
  float a0 = 0.f, a1 = 0.f;
  #pragma unroll
  for (int m = 0; m < 32; m += 2){
    a0 = fmaf(h[m],   w3[m * 192 + c],      a0);
    a1 = fmaf(h[m+1], w3[(m+1) * 192 + c],  a1);
  }
  return a0 + a1;
}

__global__ __launch_bounds__(TPB) void edge_kernel(
    const float* __restrict__ feat0, const float* __restrict__ feat1,
    const float* __restrict__ wE,    const float* __restrict__ radial,
    const float* __restrict__ b00,   const float* __restrict__ b01,
    const float* __restrict__ b10,   const float* __restrict__ b11,
    const int* __restrict__ src_idx,
    P4 W0, P4 W1, P4 W2, P4 W3,
    float* __restrict__ out)
{
  __shared__ float lds[TPB * ARENA];          // 42,496 B
  const int tid = threadIdx.x;
  const int e = blockIdx.x * TPB + tid;
  float* A = lds + tid * ARENA;               // odd stride: 2-way bank aliasing (free)

  // ---- stage edge features f32: ef[0..15] = w row, ef[16] = radial ----
  {
    const float4* wp = (const float4*)(wE + (size_t)e * 16);
    float4 a = wp[0], b = wp[1], c = wp[2], d = wp[3];
    A[0]=a.x;  A[1]=a.y;  A[2]=a.z;  A[3]=a.w;
    A[4]=b.x;  A[5]=b.y;  A[6]=b.z;  A[7]=b.w;
    A[8]=c.x;  A[9]=c.y;  A[10]=c.z; A[11]=c.w;
    A[12]=d.x; A[13]=d.y; A[14]=d.z; A[15]=d.w;
    A[16] = radial[e];
  }
  const int idx = src_idx[e];
  {
    const float4* f0 = (const float4*)(feat0 + (size_t)idx * 8);
    float4 a = f0[0], b = f0[1];
    A[50]=a.x; A[51]=a.y; A[52]=a.z; A[53]=a.w;
    A[54]=b.x; A[55]=b.y; A[56]=b.z; A[57]=b.w;
    const float4* f1 = (const float4*)(feat1 + (size_t)idx * 24);
    #pragma unroll
    for (int j = 0; j < 6; ++j){
      float4 v = f1[j];
      A[58 + 4*j + 0] = v.x; A[58 + 4*j + 1] = v.y;
      A[58 + 4*j + 2] = v.z; A[58 + 4*j + 3] = v.w;
    }
  }

  float msg0[8], msg1[24];

  // ================= pair (0,0): msg0[o] = b * sum_i R[o,i]*s0[i] =================
  {
    float h2[32];
    mlp_f32(A, W0, h2);
    const float bB = b00[e];
    float acc[8];
    #pragma unroll
    for (int o = 0; o < 8; ++o) acc[o] = 0.f;
    #pragma unroll 1
    for (int i = 0; i < 8; ++i){
      float si = A[50 + i];
      #pragma unroll
      for (int o = 0; o < 8; ++o){
        float r = W0.b3[o*8 + i] + coldot64(h2, W0.w3, o*8 + i);
        acc[o] = fmaf(r, si, acc[o]);
      }
    }
    #pragma unroll
    for (int o = 0; o < 8; ++o) msg0[o] = acc[o] * bB;
  }

  // ================= pair (0,1): msg1[o,p] = B[p] * sum_i R[o,i]*s0[i] ============
  {
    float h2[32];
    mlp_f32(A, W1, h2);
    float B0 = b01[(size_t)e*3+0];
    float B1 = b01[(size_t)e*3+1];
    float B2 = b01[(size_t)e*3+2];
    float acc[8];
    #pragma unroll
    for (int o = 0; o < 8; ++o) acc[o] = 0.f;
    #pragma unroll 1
    for (int i = 0; i < 8; ++i){
      float si = A[50 + i];
      #pragma unroll
      for (int o = 0; o < 8; ++o){
        float r = W1.b3[o*8 + i] + coldot64(h2, W1.w3, o*8 + i);
        acc[o] = fmaf(r, si, acc[o]);
      }
    }
    #pragma unroll
    for (int o = 0; o < 8; ++o){
      msg1[o*3+0] = acc[o] * B0;
      msg1[o*3+1] = acc[o] * B1;
      msg1[o*3+2] = acc[o] * B2;
    }
  }

  // ================= pair (1,0): msg0[o] += sum_i R[o,i] * (sum_q B[q]*s1[i,q]) ===
  {
    float h2[32];
    mlp_f32(A, W2, h2);
    float B0 = b10[(size_t)e*3+0];
    float B1 = b10[(size_t)e*3+1];
    float B2 = b10[(size_t)e*3+2];
    float acc[8];
    #pragma unroll
    for (int o = 0; o < 8; ++o) acc[o] = 0.f;
    #pragma unroll 1
    for (int i = 0; i < 8; ++i){
      float q0 = A[58 + 3*i + 0], q1 = A[58 + 3*i + 1], q2 = A[58 + 3*i + 2];
      float U = fmaf(B0, q0, fmaf(B1, q1, B2 * q2));
      #pragma unroll
      for (int o = 0; o < 8; ++o){
        float r = W2.b3[o*8 + i] + coldot64(h2, W2.w3, o*8 + i);
        acc[o] = fmaf(r, U, acc[o]);
      }
    }
    #pragma unroll
    for (int o = 0; o < 8; ++o) msg0[o] += acc[o];
  }

  // ---- store out0: [E,8,1] f32 ----
  {
    float* o0 = out + (size_t)e * 8;
    ((float4*)o0)[0] = make_float4(msg0[0], msg0[1], msg0[2], msg0[3]);
    ((float4*)o0)[1] = make_float4(msg0[4], msg0[5], msg0[6], msg0[7]);
  }

  // ================= pair (1,1): msg1[o,p] += sum_{i,f,q} R[o,i,f]B[p,q,f]s1[i,q] =
  {
    float h2[32];
    mlp_f32(A, W3, h2);
    float Bv[27];
    const float* __restrict__ bp = b11 + (size_t)e * 27;   // [p][q][f] = p*9+q*3+f
    #pragma unroll
    for (int j = 0; j < 27; ++j) Bv[j] = bp[j];
    #pragma unroll 1
    for (int i = 0; i < 8; ++i){
      float q0 = A[58 + 3*i + 0], q1 = A[58 + 3*i + 1], q2 = A[58 + 3*i + 2];
      float C[9];                                          // C[p,f] = sum_q B[p,q,f]*s1[i,q]
      #pragma unroll
      for (int p = 0; p < 3; ++p){
        #pragma unroll
        for (int f = 0; f < 3; ++f){
          C[p*3+f] = fmaf(Bv[p*9 + 0 + f], q0,
                     fmaf(Bv[p*9 + 3 + f], q1, Bv[p*9 + 6 + f] * q2));
        }
      }
      #pragma unroll
      for (int o = 0; o < 8; ++o){
        const int c = (o*8 + i) * 3;                       // col = o*24 + i*3 + f
        float r0 = W3.b3[c+0] + coldot192(h2, W3.w3, c+0);
        float r1 = W3.b3[c+1] + coldot192(h2, W3.w3, c+1);
        float r2 = W3.b3[c+2] + coldot192(h2, W3.w3, c+2);
        #pragma unroll
        for (int p = 0; p < 3; ++p)
          msg1[o*3+p] = fmaf(r0, C[p*3+0],
                        fmaf(r1, C[p*3+1],
                        fmaf(r2, C[p*3+2], msg1[o*3+p])));
      }
    }
  }

  // ---- store out1: [E,8,3] f32 at element offset E*8 ----
  {
    float* o1 = out + (size_t)E_TOT * 8 + (size_t)e * 24;
    #pragma unroll
    for (int j = 0; j < 6; ++j)
      ((float4*)o1)[j] = make_float4(msg1[4*j+0], msg1[4*j+1], msg1[4*j+2], msg1[4*j+3]);
  }
}

extern "C" void kernel_launch(void* const* d_in, const int* in_sizes, int n_in,
                              void* d_out, int out_size, void* d_ws, size_t ws_size,
                              hipStream_t stream)
{
  const float* feat0 = (const float*)d_in[0];
  const float* feat1 = (const float*)d_in[1];
  const float* wE    = (const float*)d_in[2];
  const float* rad   = (const float*)d_in[3];
  const float* b00   = (const float*)d_in[4];
  const float* b01   = (const float*)d_in[11];
  const float* b10   = (const float*)d_in[18];
  const float* b11   = (const float*)d_in[25];
  const int* sidx    = (const int*)d_in[32];

  P4 W[4];
  for (int p = 0; p < 4; ++p){
    W[p].w1 = (const float*)d_in[5  + 7*p];
    W[p].b1 = (const float*)d_in[6  + 7*p];
    W[p].w2 = (const float*)d_in[7  + 7*p];
    W[p].b2 = (const float*)d_in[8  + 7*p];
    W[p].w3 = (const float*)d_in[9  + 7*p];
    W[p].b3 = (const float*)d_in[10 + 7*p];
  }

  edge_kernel<<<NBLK, TPB, 0, stream>>>(feat0, feat1, wE, rad, b00, b01, b10, b11,
                                        sidx, W[0], W[1], W[2], W[3], (float*)d_out);
}

// Round 5
// 598.809 us; speedup vs baseline: 1.2934x; 1.2934x over previous
//
#include <hip/hip_runtime.h>

#define E_TOT 160000
#define TPB   128
#define NBLK  1250       // 1250*128 == 160000 exactly
#define ARENA 49         // f32 words/thread: ef[0..16] | h[17..48] (h1 then h2, shared slot)

struct P4 { const float *w1, *b1, *w2, *b2, *w3, *b3; };

// radial MLP: ef in A[0..16]; h1 staged in A[17..48]; final h2 (ReLU'd) overwrites A[17..48]
__device__ __forceinline__ void mlp_lds(float* __restrict__ A, P4 W)
{
  float h[32];
  #pragma unroll
  for (int m = 0; m < 32; ++m) h[m] = W.b1[m];
  #pragma unroll 1
  for (int k = 0; k < 17; ++k){
    float x = A[k];
    const float* __restrict__ r = W.w1 + k * 32;   // contiguous row -> s_load_dwordx16
    #pragma unroll
    for (int m = 0; m < 32; ++m) h[m] = fmaf(x, r[m], h[m]);
  }
  #pragma unroll
  for (int m = 0; m < 32; ++m) A[17 + m] = fmaxf(h[m], 0.f);
  float g[32];
  #pragma unroll
  for (int m = 0; m < 32; ++m) g[m] = W.b2[m];
  #pragma unroll 1
  for (int k = 0; k < 32; ++k){
    float x = A[17 + k];
    const float* __restrict__ r = W.w2 + k * 32;   // contiguous row
    #pragma unroll
    for (int m = 0; m < 32; ++m) g[m] = fmaf(x, r[m], g[m]);
  }
  #pragma unroll
  for (int m = 0; m < 32; ++m) A[17 + m] = fmaxf(g[m], 0.f);  // h2 replaces h1
}

// acc[o] = sum_i b3[o*8+i]*v[i] + sum_m h2[m] * (sum_i w3[m*64+o*8+i]*v[i])
// (pure reassociation of R[o,i] = b3 + h2.w3col, contracted with v)
__device__ __forceinline__ void matvec64(const float* __restrict__ H /* = &A[17] */,
                                         const float* __restrict__ w3,
                                         const float* __restrict__ b3,
                                         const float (&v)[8], float (&acc)[8])
{
  #pragma unroll
  for (int o = 0; o < 8; ++o){
    float t = 0.f;
    #pragma unroll
    for (int i = 0; i < 8; ++i) t = fmaf(b3[o*8 + i], v[i], t);
    acc[o] = t;
  }
  #pragma unroll 1
  for (int m = 0; m < 32; ++m){
    const float* __restrict__ r = w3 + m * 64;     // contiguous row of 64 floats
    const float hm = H[m];                         // ds_read, dynamic m OK (LDS)
    #pragma unroll
    for (int o = 0; o < 8; ++o){
      float t = 0.f;
      #pragma unroll
      for (int i = 0; i < 8; ++i) t = fmaf(r[o*8 + i], v[i], t);
      acc[o] = fmaf(hm, t, acc[o]);
    }
  }
}

__global__ __launch_bounds__(TPB) void edge_kernel(
    const float* __restrict__ feat0, const float* __restrict__ feat1,
    const float* __restrict__ wE,    const float* __restrict__ radial,
    const float* __restrict__ b00,   const float* __restrict__ b01,
    const float* __restrict__ b10,   const float* __restrict__ b11,
    const int* __restrict__ src_idx,
    P4 W0, P4 W1, P4 W2, P4 W3,
    float* __restrict__ out)
{
  __shared__ float lds[TPB * ARENA];               // 25,088 B -> 6 blocks/CU (12 waves)
  const int tid = threadIdx.x;
  const int e = blockIdx.x * TPB + tid;
  float* A = lds + tid * ARENA;                    // stride 49 (odd): 2-way aliasing, free

  // ---- stage edge features into LDS: ef[0..15]=w row, ef[16]=radial ----
  {
    const float4* wp = (const float4*)(wE + (size_t)e * 16);
    float4 a = wp[0], b = wp[1], c = wp[2], d = wp[3];
    A[0]=a.x;  A[1]=a.y;  A[2]=a.z;  A[3]=a.w;
    A[4]=b.x;  A[5]=b.y;  A[6]=b.z;  A[7]=b.w;
    A[8]=c.x;  A[9]=c.y;  A[10]=c.z; A[11]=c.w;
    A[12]=d.x; A[13]=d.y; A[14]=d.z; A[15]=d.w;
    A[16] = radial[e];
  }
  // ---- source features -> registers (all statically indexed below) ----
  const int idx = src_idx[e];
  float s0[8], s1[24];
  {
    const float4* f0 = (const float4*)(feat0 + (size_t)idx * 8);
    float4 a = f0[0], b = f0[1];
    s0[0]=a.x; s0[1]=a.y; s0[2]=a.z; s0[3]=a.w;
    s0[4]=b.x; s0[5]=b.y; s0[6]=b.z; s0[7]=b.w;
    const float4* f1 = (const float4*)(feat1 + (size_t)idx * 24);
    #pragma unroll
    for (int j = 0; j < 6; ++j){
      float4 v = f1[j];
      s1[4*j+0]=v.x; s1[4*j+1]=v.y; s1[4*j+2]=v.z; s1[4*j+3]=v.w;
    }
  }

  float msg0[8], msg1[24];

  // ================= pair (0,0) =================
  {
    const float bB = b00[e];
    mlp_lds(A, W0);
    float acc[8];
    matvec64(A + 17, W0.w3, W0.b3, s0, acc);
    #pragma unroll
    for (int o = 0; o < 8; ++o) msg0[o] = acc[o] * bB;
  }

  // ================= pair (0,1) =================
  {
    const float B0 = b01[(size_t)e*3+0];
    const float B1 = b01[(size_t)e*3+1];
    const float B2 = b01[(size_t)e*3+2];
    mlp_lds(A, W1);
    float acc[8];
    matvec64(A + 17, W1.w3, W1.b3, s0, acc);
    #pragma unroll
    for (int o = 0; o < 8; ++o){
      msg1[o*3+0] = acc[o] * B0;
      msg1[o*3+1] = acc[o] * B1;
      msg1[o*3+2] = acc[o] * B2;
    }
  }

  // ================= pair (1,0) =================
  {
    const float B0 = b10[(size_t)e*3+0];
    const float B1 = b10[(size_t)e*3+1];
    const float B2 = b10[(size_t)e*3+2];
    mlp_lds(A, W2);
    float U[8];
    #pragma unroll
    for (int i = 0; i < 8; ++i)
      U[i] = fmaf(B0, s1[3*i+0], fmaf(B1, s1[3*i+1], B2 * s1[3*i+2]));
    float acc[8];
    matvec64(A + 17, W2.w3, W2.b3, U, acc);
    #pragma unroll
    for (int o = 0; o < 8; ++o) msg0[o] += acc[o];
  }

  // ---- store out0: [E,8,1] f32 ----
  {
    float* o0 = out + (size_t)e * 8;
    ((float4*)o0)[0] = make_float4(msg0[0], msg0[1], msg0[2], msg0[3]);
    ((float4*)o0)[1] = make_float4(msg0[4], msg0[5], msg0[6], msg0[7]);
  }

  // ================= pair (1,1) =================
  {
    float Bv[27];
    const float* __restrict__ bp = b11 + (size_t)e * 27;   // [p][q][f] = p*9+q*3+f
    #pragma unroll
    for (int j = 0; j < 27; ++j) Bv[j] = bp[j];
    mlp_lds(A, W3);
    // C[i,p,f] = sum_q Bv[p*9+q*3+f] * s1[i*3+q]   (72 regs, built once)
    float C[72];
    #pragma unroll
    for (int i = 0; i < 8; ++i){
      #pragma unroll
      for (int p = 0; p < 3; ++p){
        #pragma unroll
        for (int f = 0; f < 3; ++f){
          C[i*9 + p*3 + f] = fmaf(Bv[p*9 + 0 + f], s1[3*i+0],
                             fmaf(Bv[p*9 + 3 + f], s1[3*i+1],
                                  Bv[p*9 + 6 + f] * s1[3*i+2]));
        }
      }
    }
    const float* __restrict__ H = A + 17;
    #pragma unroll
    for (int o = 0; o < 8; ++o){                    // fully unrolled: msg1 stays static
      float a24[24];                                // R[o,i,f] = a24[i*3+f]
      const float* __restrict__ b3o = W3.b3 + o * 24;
      #pragma unroll
      for (int j = 0; j < 24; ++j) a24[j] = b3o[j];
      #pragma unroll 1
      for (int m = 0; m < 32; ++m){
        const float* __restrict__ r = W3.w3 + m * 192 + o * 24;  // 24-contig row segment
        const float hm = H[m];
        #pragma unroll
        for (int j = 0; j < 24; ++j) a24[j] = fmaf(hm, r[j], a24[j]);
      }
      #pragma unroll
      for (int p = 0; p < 3; ++p){
        float t = msg1[o*3 + p];
        #pragma unroll
        for (int i = 0; i < 8; ++i){
          #pragma unroll
          for (int f = 0; f < 3; ++f)
            t = fmaf(a24[i*3 + f], C[i*9 + p*3 + f], t);
        }
        msg1[o*3 + p] = t;
      }
    }
  }

  // ---- store out1: [E,8,3] f32 at element offset E*8 ----
  {
    float* o1 = out + (size_t)E_TOT * 8 + (size_t)e * 24;
    #pragma unroll
    for (int j = 0; j < 6; ++j)
      ((float4*)o1)[j] = make_float4(msg1[4*j+0], msg1[4*j+1], msg1[4*j+2], msg1[4*j+3]);
  }
}

extern "C" void kernel_launch(void* const* d_in, const int* in_sizes, int n_in,
                              void* d_out, int out_size, void* d_ws, size_t ws_size,
                              hipStream_t stream)
{
  const float* feat0 = (const float*)d_in[0];
  const float* feat1 = (const float*)d_in[1];
  const float* wE    = (const float*)d_in[2];
  const float* rad   = (const float*)d_in[3];
  const float* b00   = (const float*)d_in[4];
  const float* b01   = (const float*)d_in[11];
  const float* b10   = (const float*)d_in[18];
  const float* b11   = (const float*)d_in[25];
  const int* sidx    = (const int*)d_in[32];

  P4 W[4];
  for (int p = 0; p < 4; ++p){
    W[p].w1 = (const float*)d_in[5  + 7*p];
    W[p].b1 = (const float*)d_in[6  + 7*p];
    W[p].w2 = (const float*)d_in[7  + 7*p];
    W[p].b2 = (const float*)d_in[8  + 7*p];
    W[p].w3 = (const float*)d_in[9  + 7*p];
    W[p].b3 = (const float*)d_in[10 + 7*p];
  }

  edge_kernel<<<NBLK, TPB, 0, stream>>>(feat0, feat1, wE, rad, b00, b01, b10, b11,
                                        sidx, W[0], W[1], W[2], W[3], (float*)d_out);
}

// Round 6
// 345.826 us; speedup vs baseline: 2.2396x; 1.7315x over previous
//
#include <hip/hip_runtime.h>

#define E_TOT 160000
#define TPB   128
#define NBLK  1250       // 1250*128 == 160000 exactly
#define ARENA 49         // f32 words/thread: ef[0..16] | h[17..48] (h1 then h2 share slot)

struct P4 { const float *w1, *b1, *w2, *b2, *w3, *b3; };

__global__ __launch_bounds__(TPB, 3) void edge_kernel(
    const float* __restrict__ feat0, const float* __restrict__ feat1,
    const float* __restrict__ wE,    const float* __restrict__ radial,
    const float* __restrict__ b00,   const float* __restrict__ b01,
    const float* __restrict__ b10,   const float* __restrict__ b11,
    const int* __restrict__ src_idx,
    P4 W0, P4 W1, P4 W2, P4 W3,
    float* __restrict__ out)
{
  __shared__ float lds[TPB * ARENA];               // 25,088 B -> 6 blocks/CU
  const int tid = threadIdx.x;
  const int e = blockIdx.x * TPB + tid;
  float* A = lds + tid * ARENA;                    // stride 49 (odd): 2-way aliasing = free

  // ---- early per-edge scalars (independent loads, issue up front) ----
  const float bB = b00[e];
  float B01[3], B10[3];
  #pragma unroll
  for (int q = 0; q < 3; ++q){
    B01[q] = b01[(size_t)e*3 + q];
    B10[q] = b10[(size_t)e*3 + q];
  }

  // ---- stage edge features into LDS: ef[0..15]=w row, ef[16]=radial ----
  {
    const float4* wp = (const float4*)(wE + (size_t)e * 16);
    float4 a = wp[0], b = wp[1], c = wp[2], d = wp[3];
    A[0]=a.x;  A[1]=a.y;  A[2]=a.z;  A[3]=a.w;
    A[4]=b.x;  A[5]=b.y;  A[6]=b.z;  A[7]=b.w;
    A[8]=c.x;  A[9]=c.y;  A[10]=c.z; A[11]=c.w;
    A[12]=d.x; A[13]=d.y; A[14]=d.z; A[15]=d.w;
    A[16] = radial[e];
  }
  // ---- source features -> registers ----
  const int idx = src_idx[e];
  float s0[8], s1[24];
  {
    const float4* f0 = (const float4*)(feat0 + (size_t)idx * 8);
    float4 a = f0[0], b = f0[1];
    s0[0]=a.x; s0[1]=a.y; s0[2]=a.z; s0[3]=a.w;
    s0[4]=b.x; s0[5]=b.y; s0[6]=b.z; s0[7]=b.w;
    const float4* f1 = (const float4*)(feat1 + (size_t)idx * 24);
    #pragma unroll
    for (int j = 0; j < 6; ++j){
      float4 v = f1[j];
      s1[4*j+0]=v.x; s1[4*j+1]=v.y; s1[4*j+2]=v.z; s1[4*j+3]=v.w;
    }
  }
  // U[i] = sum_q B10[q]*s1[i,q]  (pair (1,0) contracted source)
  float U[8];
  #pragma unroll
  for (int i = 0; i < 8; ++i)
    U[i] = fmaf(B10[0], s1[3*i+0], fmaf(B10[1], s1[3*i+1], B10[2]*s1[3*i+2]));

  float msg0[8], t01[8];

  // ================= unified phase loop: p=0,1,2 -> matvec64 pairs; p=3 -> (1,1) ====
  #pragma unroll 1
  for (int p = 0; p < 4; ++p){
    const float* __restrict__ w1 = (p==0)?W0.w1:(p==1)?W1.w1:(p==2)?W2.w1:W3.w1;
    const float* __restrict__ b1 = (p==0)?W0.b1:(p==1)?W1.b1:(p==2)?W2.b1:W3.b1;
    const float* __restrict__ w2 = (p==0)?W0.w2:(p==1)?W1.w2:(p==2)?W2.w2:W3.w2;
    const float* __restrict__ b2 = (p==0)?W0.b2:(p==1)?W1.b2:(p==2)?W2.b2:W3.b2;
    const float* __restrict__ w3 = (p==0)?W0.w3:(p==1)?W1.w3:(p==2)?W2.w3:W3.w3;
    const float* __restrict__ b3 = (p==0)?W0.b3:(p==1)?W1.b3:(p==2)?W2.b3:W3.b3;

    // ---------- radial MLP (one I$ copy): ef -> h2 in A[17..48] ----------
    {
      float h[32];
      #pragma unroll
      for (int m = 0; m < 32; ++m) h[m] = b1[m];
      #pragma unroll 1
      for (int c = 0; c < 2; ++c){                 // k-chunks of 8
        float x[8];
        #pragma unroll
        for (int j = 0; j < 8; ++j) x[j] = A[c*8 + j];
        const float* __restrict__ r = w1 + c * 256;
        #pragma unroll
        for (int j = 0; j < 8; ++j){
          #pragma unroll
          for (int m = 0; m < 32; ++m) h[m] = fmaf(x[j], r[j*32 + m], h[m]);
        }
      }
      {                                            // k = 16 tail (radial)
        float x = A[16];
        const float* __restrict__ r = w1 + 512;
        #pragma unroll
        for (int m = 0; m < 32; ++m) h[m] = fmaf(x, r[m], h[m]);
      }
      #pragma unroll
      for (int m = 0; m < 32; ++m) A[17 + m] = fmaxf(h[m], 0.f);
      float g[32];
      #pragma unroll
      for (int m = 0; m < 32; ++m) g[m] = b2[m];
      #pragma unroll 1
      for (int c = 0; c < 4; ++c){                 // k-chunks of 8
        float x[8];
        #pragma unroll
        for (int j = 0; j < 8; ++j) x[j] = A[17 + c*8 + j];
        const float* __restrict__ r = w2 + c * 256;
        #pragma unroll
        for (int j = 0; j < 8; ++j){
          #pragma unroll
          for (int m = 0; m < 32; ++m) g[m] = fmaf(x[j], r[j*32 + m], g[m]);
        }
      }
      #pragma unroll
      for (int m = 0; m < 32; ++m) A[17 + m] = fmaxf(g[m], 0.f);   // h2 replaces h1
    }

    if (p < 3){
      // ---------- layer-3 matvec, 64 cols: acc[o] = b3-term + sum_m h2[m]*(row.v) ---
      float v[8];
      #pragma unroll
      for (int i = 0; i < 8; ++i) v[i] = (p == 2) ? U[i] : s0[i];
      float acc[8];
      #pragma unroll
      for (int o = 0; o < 8; ++o){
        float t = 0.f;
        #pragma unroll
        for (int i = 0; i < 8; ++i) t = fmaf(b3[o*8 + i], v[i], t);
        acc[o] = t;
      }
      #pragma unroll 1
      for (int c = 0; c < 4; ++c){                 // m-chunks of 8
        float hh[8];
        #pragma unroll
        for (int j = 0; j < 8; ++j) hh[j] = A[17 + c*8 + j];
        const float* __restrict__ rb = w3 + c * 512;
        #pragma unroll
        for (int j = 0; j < 8; ++j){
          const float* __restrict__ r = rb + j * 64;
          #pragma unroll
          for (int o = 0; o < 8; ++o){
            float t = 0.f;
            #pragma unroll
            for (int i = 0; i < 8; ++i) t = fmaf(r[o*8 + i], v[i], t);
            acc[o] = fmaf(hh[j], t, acc[o]);
          }
        }
      }
      if (p == 0){
        #pragma unroll
        for (int o = 0; o < 8; ++o) msg0[o] = acc[o] * bB;
      } else if (p == 1){
        #pragma unroll
        for (int o = 0; o < 8; ++o) t01[o] = acc[o];
      } else {
        #pragma unroll
        for (int o = 0; o < 8; ++o) msg0[o] += acc[o];
      }
    } else {
      // ---------- pair (1,1): per-o R-slice build + D-contraction ----------
      float Bv[27];
      const float* __restrict__ bp = b11 + (size_t)e * 27;   // [p][q][f]
      #pragma unroll
      for (int j = 0; j < 27; ++j) Bv[j] = bp[j];
      // ef slot A[0..16] is dead now (last MLP done) -> park t01 for dynamic-o access
      #pragma unroll
      for (int j = 0; j < 8; ++j) A[j] = t01[j];
      float* __restrict__ o1 = out + (size_t)E_TOT * 8 + (size_t)e * 24;
      #pragma unroll 1
      for (int o = 0; o < 8; ++o){
        float a24[24];                              // R[o,i,f] = a24[i*3+f]
        const float* __restrict__ b3o = b3 + o * 24;
        #pragma unroll
        for (int j = 0; j < 24; ++j) a24[j] = b3o[j];
        #pragma unroll 1
        for (int c = 0; c < 4; ++c){                // m-chunks of 8
          float hh[8];
          #pragma unroll
          for (int j = 0; j < 8; ++j) hh[j] = A[17 + c*8 + j];
          const float* __restrict__ rb = w3 + c * 1536 + o * 24;
          #pragma unroll
          for (int jj = 0; jj < 8; ++jj){
            const float* __restrict__ r = rb + jj * 192;    // 24-contig segment
            #pragma unroll
            for (int j = 0; j < 24; ++j) a24[j] = fmaf(hh[jj], r[j], a24[j]);
          }
        }
        // D[q,f] = sum_i R[o,i,f] * s1[i,q]
        float D[9];
        #pragma unroll
        for (int q = 0; q < 3; ++q){
          #pragma unroll
          for (int f = 0; f < 3; ++f){
            float t = 0.f;
            #pragma unroll
            for (int i = 0; i < 8; ++i) t = fmaf(a24[i*3 + f], s1[i*3 + q], t);
            D[q*3 + f] = t;
          }
        }
        const float t01o = A[o];                    // parked value, dynamic o via LDS
        #pragma unroll
        for (int pp = 0; pp < 3; ++pp){
          float t = t01o * B01[pp];                 // pair (0,1) rank-1 contribution
          #pragma unroll
          for (int q = 0; q < 3; ++q){
            #pragma unroll
            for (int f = 0; f < 3; ++f)
              t = fmaf(Bv[pp*9 + q*3 + f], D[q*3 + f], t);
          }
          o1[o*3 + pp] = t;                         // L2 write-combines
        }
      }
    }
  }

  // ---- store out0: [E,8,1] f32 ----
  {
    float* o0 = out + (size_t)e * 8;
    ((float4*)o0)[0] = make_float4(msg0[0], msg0[1], msg0[2], msg0[3]);
    ((float4*)o0)[1] = make_float4(msg0[4], msg0[5], msg0[6], msg0[7]);
  }
}

extern "C" void kernel_launch(void* const* d_in, const int* in_sizes, int n_in,
                              void* d_out, int out_size, void* d_ws, size_t ws_size,
                              hipStream_t stream)
{
  const float* feat0 = (const float*)d_in[0];
  const float* feat1 = (const float*)d_in[1];
  const float* wE    = (const float*)d_in[2];
  const float* rad   = (const float*)d_in[3];
  const float* b00   = (const float*)d_in[4];
  const float* b01   = (const float*)d_in[11];
  const float* b10   = (const float*)d_in[18];
  const float* b11   = (const float*)d_in[25];
  const int* sidx    = (const int*)d_in[32];

  P4 W[4];
  for (int p = 0; p < 4; ++p){
    W[p].w1 = (const float*)d_in[5  + 7*p];
    W[p].b1 = (const float*)d_in[6  + 7*p];
    W[p].w2 = (const float*)d_in[7  + 7*p];
    W[p].b2 = (const float*)d_in[8  + 7*p];
    W[p].w3 = (const float*)d_in[9  + 7*p];
    W[p].b3 = (const float*)d_in[10 + 7*p];
  }

  edge_kernel<<<NBLK, TPB, 0, stream>>>(feat0, feat1, wE, rad, b00, b01, b10, b11,
                                        sidx, W[0], W[1], W[2], W[3], (float*)d_out);
}